// Round 1
// baseline (1896.279 us; speedup 1.0000x reference)
//
#include <hip/hip_runtime.h>
#include <hip/hip_bf16.h>
#include <cstdint>
#include <cstddef>

// ---------------------------------------------------------------------------
// SparseTransformerLayer on MI355X (gfx950)
// N_NODES=50000, N_EDGES=400000, D=256, H=4, HD=64
// Strategy: bf16 MFMA (16x16x32) for all GEMMs, m97-style global_load_lds
// staging, scores fused into KV-GEMM epilogue (K never materialized),
// CSR-based segment softmax + aggregation, fp32 LayerNorms.
// ---------------------------------------------------------------------------

typedef __bf16 bf16;
typedef bf16 bf16x8 __attribute__((ext_vector_type(8)));
typedef bf16 bf16x4v __attribute__((ext_vector_type(4)));
typedef float f32x4 __attribute__((ext_vector_type(4)));
typedef const uint32_t __attribute__((address_space(1)))* gas_u32p;
typedef uint32_t __attribute__((address_space(3)))* las_u32p;

#define DEV static __device__ __forceinline__

static constexpr int NN = 50000;
static constexpr int NE = 400000;

DEV void async_copy16(const void* g, void* l) {
  __builtin_amdgcn_global_load_lds((gas_u32p)g, (las_u32p)l, 16, 0, 0);
}
DEV float bf2f(bf16 x) { return (float)x; }
DEV bf16  f2bf(float x) { return (bf16)x; }

// ---------------------------------------------------------------------------
// Edge GEMM: A[row e][k] = (k<256 ? h_n[idx[e]][k] : h_e[e][k-256]), K=512.
// B = WT [Nout][512] (pre-transposed bf16). 128x128 tile, BK=32, 4 waves in
// 2x2 quadrants of 64x64. KV==0: write Q (+bias) bf16. KV==1: cols<256 fuse
// scores (per-wave head), cols>=256 write V (+bias) bf16.
// ---------------------------------------------------------------------------
template <int KV>
__global__ __launch_bounds__(256, 2) void gemm_edge(
    const bf16* __restrict__ hn, const bf16* __restrict__ he,
    const int* __restrict__ idx, const bf16* __restrict__ WT,
    const float* __restrict__ bias, const bf16* __restrict__ Qbf,
    bf16* __restrict__ outbf, float* __restrict__ scores) {
  __shared__ bf16 Al[128 * 32];
  __shared__ bf16 Bl[128 * 32];
  const int tid = threadIdx.x;
  const int e0 = blockIdx.x * 128;
  const int n0 = blockIdx.y * 128;

  // Staging: chunk c = tid + 256p covers 16B; row=c>>2, k-offset=(c&3)*8.
  const bf16* an[2];
  const bf16* ae[2];
  const bf16* bb[2];
#pragma unroll
  for (int p = 0; p < 2; ++p) {
    int c = tid + 256 * p;
    int row = c >> 2;
    int c8 = (c & 3) * 8;
    int e = e0 + row;
    int node = idx[e];
    an[p] = hn + (size_t)node * 256 + c8;
    ae[p] = he + (size_t)e * 256 + c8;
    bb[p] = WT + (size_t)(n0 + row) * 512 + c8;
  }

  const int wv = tid >> 6, lane = tid & 63;
  const int quad = lane >> 4, l16 = lane & 15;
  const int wrow = (wv >> 1) * 64, wcol = (wv & 1) * 64;

  f32x4 acc[4][4] = {};

  for (int k0 = 0; k0 < 512; k0 += 32) {
    if (k0) __syncthreads();
#pragma unroll
    for (int p = 0; p < 2; ++p) {
      const bf16* ga = (k0 < 256) ? (an[p] + k0) : (ae[p] + (k0 - 256));
      async_copy16(ga, &Al[(tid + 256 * p) * 8]);
      async_copy16(bb[p] + k0, &Bl[(tid + 256 * p) * 8]);
    }
    __syncthreads();
    bf16x8 af[4], bfr[4];
#pragma unroll
    for (int t = 0; t < 4; ++t)
      af[t] = *(const bf16x8*)&Al[(wrow + t * 16 + l16) * 32 + quad * 8];
#pragma unroll
    for (int t = 0; t < 4; ++t)
      bfr[t] = *(const bf16x8*)&Bl[(wcol + t * 16 + l16) * 32 + quad * 8];
#pragma unroll
    for (int mt = 0; mt < 4; ++mt)
#pragma unroll
      for (int nt = 0; nt < 4; ++nt)
        acc[mt][nt] = __builtin_amdgcn_mfma_f32_16x16x32_bf16(
            af[mt], bfr[nt], acc[mt][nt], 0, 0, 0);
  }

  // C/D layout: col = l16 (per nt tile), row = quad*4 + r (per mt tile).
  if (KV == 0) {
#pragma unroll
    for (int nt = 0; nt < 4; ++nt) {
      int col = n0 + wcol + nt * 16 + l16;
      float bv = bias[col];
#pragma unroll
      for (int mt = 0; mt < 4; ++mt)
#pragma unroll
        for (int r = 0; r < 4; ++r) {
          int row = e0 + wrow + mt * 16 + quad * 4 + r;
          outbf[(size_t)row * 256 + col] = f2bf(acc[mt][nt][r] + bv);
        }
    }
  } else if (blockIdx.y < 2) {
    // K region: fused scores. Wave's 64 cols == one head.
    const int head = (n0 + wcol) >> 6;
    float bv[4];
#pragma unroll
    for (int nt = 0; nt < 4; ++nt) bv[nt] = bias[n0 + wcol + nt * 16 + l16];
#pragma unroll
    for (int mt = 0; mt < 4; ++mt)
#pragma unroll
      for (int r = 0; r < 4; ++r) {
        int row = e0 + wrow + mt * 16 + quad * 4 + r;
        float part = 0.f;
#pragma unroll
        for (int nt = 0; nt < 4; ++nt) {
          int col = n0 + wcol + nt * 16 + l16;
          part += (acc[mt][nt][r] + bv[nt]) * bf2f(Qbf[(size_t)row * 256 + col]);
        }
        part += __shfl_xor(part, 1);
        part += __shfl_xor(part, 2);
        part += __shfl_xor(part, 4);
        part += __shfl_xor(part, 8);
        if (l16 == 0) scores[(size_t)row * 4 + head] = part * 0.125f;  // /sqrt(64)
      }
  } else {
    // V region
#pragma unroll
    for (int nt = 0; nt < 4; ++nt) {
      int col = n0 + wcol + nt * 16 + l16;  // 256..511
      float bv = bias[col];
#pragma unroll
      for (int mt = 0; mt < 4; ++mt)
#pragma unroll
        for (int r = 0; r < 4; ++r) {
          int row = e0 + wrow + mt * 16 + quad * 4 + r;
          outbf[(size_t)row * 256 + (col - 256)] = f2bf(acc[mt][nt][r] + bv);
        }
    }
  }
}

// ---------------------------------------------------------------------------
// Node GEMM: A [M][KT] bf16 (row-clamped), B = WT [Nout][KT].
// EPI 0: outf = acc + bias (f32). EPI 1: outb = bf16(gelu(acc + bias)).
// ---------------------------------------------------------------------------
template <int KT, int EPI>
__global__ __launch_bounds__(256, 2) void gemm_node(
    const bf16* __restrict__ A, int M, const bf16* __restrict__ WT,
    const float* __restrict__ bias, int Nout, float* __restrict__ outf,
    bf16* __restrict__ outb) {
  __shared__ bf16 Al[128 * 32];
  __shared__ bf16 Bl[128 * 32];
  const int tid = threadIdx.x;
  const int m0 = blockIdx.x * 128;
  const int n0 = blockIdx.y * 128;
  const bf16* ab[2];
  const bf16* bb[2];
#pragma unroll
  for (int p = 0; p < 2; ++p) {
    int c = tid + 256 * p;
    int row = c >> 2;
    int c8 = (c & 3) * 8;
    int rg = m0 + row;
    if (rg > M - 1) rg = M - 1;  // clamp; stores are guarded
    ab[p] = A + (size_t)rg * KT + c8;
    bb[p] = WT + (size_t)(n0 + row) * KT + c8;
  }
  const int wv = tid >> 6, lane = tid & 63;
  const int quad = lane >> 4, l16 = lane & 15;
  const int wrow = (wv >> 1) * 64, wcol = (wv & 1) * 64;
  f32x4 acc[4][4] = {};
  for (int k0 = 0; k0 < KT; k0 += 32) {
    if (k0) __syncthreads();
#pragma unroll
    for (int p = 0; p < 2; ++p) {
      async_copy16(ab[p] + k0, &Al[(tid + 256 * p) * 8]);
      async_copy16(bb[p] + k0, &Bl[(tid + 256 * p) * 8]);
    }
    __syncthreads();
    bf16x8 af[4], bfr[4];
#pragma unroll
    for (int t = 0; t < 4; ++t)
      af[t] = *(const bf16x8*)&Al[(wrow + t * 16 + l16) * 32 + quad * 8];
#pragma unroll
    for (int t = 0; t < 4; ++t)
      bfr[t] = *(const bf16x8*)&Bl[(wcol + t * 16 + l16) * 32 + quad * 8];
#pragma unroll
    for (int mt = 0; mt < 4; ++mt)
#pragma unroll
      for (int nt = 0; nt < 4; ++nt)
        acc[mt][nt] = __builtin_amdgcn_mfma_f32_16x16x32_bf16(
            af[mt], bfr[nt], acc[mt][nt], 0, 0, 0);
  }
#pragma unroll
  for (int nt = 0; nt < 4; ++nt) {
    int col = n0 + wcol + nt * 16 + l16;
    float bv = bias[col];
#pragma unroll
    for (int mt = 0; mt < 4; ++mt)
#pragma unroll
      for (int r = 0; r < 4; ++r) {
        int row = m0 + wrow + mt * 16 + quad * 4 + r;
        if (row < M) {
          float v = acc[mt][nt][r] + bv;
          if (EPI == 0)
            outf[(size_t)row * Nout + col] = v;
          else
            outb[(size_t)row * Nout + col] =
                f2bf(0.5f * v * (1.f + erff(v * 0.70710678118654752f)));
        }
      }
  }
}

// --------------------------- utility kernels -------------------------------
__global__ __launch_bounds__(256) void cast_bf16(const float* __restrict__ in,
                                                 bf16* __restrict__ out, int n) {
  int i = (blockIdx.x * 256 + threadIdx.x) * 4;
  if (i < n) {
    float4 v = *(const float4*)(in + i);
    bf16x4v o = {f2bf(v.x), f2bf(v.y), f2bf(v.z), f2bf(v.w)};
    *(bf16x4v*)(out + i) = o;
  }
}

// W [K][N] f32  ->  WT [N][K] bf16
__global__ __launch_bounds__(256) void transpose_cast(
    const float* __restrict__ W, bf16* __restrict__ WT, int K, int N) {
  int i = blockIdx.x * 256 + threadIdx.x;
  if (i < K * N) {
    int k = i / N, n = i - k * N;
    WT[(size_t)n * K + k] = f2bf(W[i]);
  }
}

__global__ __launch_bounds__(256) void count_deg(const int* __restrict__ src,
                                                 int* __restrict__ deg, int nE) {
  int e = blockIdx.x * 256 + threadIdx.x;
  if (e < nE) atomicAdd(&deg[src[e]], 1);
}

// single-block exclusive scan over deg -> offs (nN+1), also copies to cursor
__global__ __launch_bounds__(256) void scan_offs(const int* __restrict__ deg,
                                                 int* __restrict__ offs,
                                                 int* __restrict__ cursor,
                                                 int nN) {
  __shared__ int part[256];
  int tid = threadIdx.x;
  int per = (nN + 255) >> 8;
  int lo = tid * per, hi = lo + per;
  if (hi > nN) hi = nN;
  int sm = 0;
  for (int i = lo; i < hi; ++i) sm += deg[i];
  part[tid] = sm;
  __syncthreads();
  if (tid == 0) {
    int run = 0;
    for (int i = 0; i < 256; ++i) {
      int v = part[i];
      part[i] = run;
      run += v;
    }
  }
  __syncthreads();
  int run = part[tid];
  for (int i = lo; i < hi; ++i) {
    offs[i] = run;
    cursor[i] = run;
    run += deg[i];
  }
  if (tid == 255) offs[nN] = run;
}

__global__ __launch_bounds__(256) void scatter_edges(const int* __restrict__ src,
                                                     int* __restrict__ cursor,
                                                     int* __restrict__ eperm,
                                                     int nE) {
  int e = blockIdx.x * 256 + threadIdx.x;
  if (e < nE) {
    int p = atomicAdd(&cursor[src[e]], 1);
    eperm[p] = e;
  }
}

// per-node segment softmax + weighted V sum. block = node, 256 thr (wave=head
// for max/denom phases, thread=channel for accumulate phase).
__global__ __launch_bounds__(256) void aggregate(
    const int* __restrict__ offs, const int* __restrict__ eperm,
    const float* __restrict__ scores, const bf16* __restrict__ Vbf,
    bf16* __restrict__ outbf) {
  int n = blockIdx.x;
  int s = offs[n];
  int deg = offs[n + 1] - s;
  int tid = threadIdx.x, wv = tid >> 6, lane = tid & 63;
  __shared__ float mdl[4], dnl[4];
  float mx = -3.4e38f;
  for (int i = lane; i < deg; i += 64) {
    int e = eperm[s + i];
    mx = fmaxf(mx, scores[(size_t)e * 4 + wv]);
  }
#pragma unroll
  for (int o = 32; o; o >>= 1) mx = fmaxf(mx, __shfl_xor(mx, o));
  float sm = 0.f;
  for (int i = lane; i < deg; i += 64) {
    int e = eperm[s + i];
    sm += expf(scores[(size_t)e * 4 + wv] - mx);
  }
#pragma unroll
  for (int o = 32; o; o >>= 1) sm += __shfl_xor(sm, o);
  if (lane == 0) {
    mdl[wv] = mx;
    dnl[wv] = sm;
  }
  __syncthreads();
  int c = tid, h = tid >> 6;
  float m = mdl[h];
  float rd = dnl[h] > 0.f ? 1.f / dnl[h] : 0.f;
  float acc = 0.f;
  for (int i = 0; i < deg; ++i) {
    int e = eperm[s + i];
    float w = expf(scores[(size_t)e * 4 + h] - m) * rd;
    acc += w * bf2f(Vbf[(size_t)e * 256 + c]);
  }
  outbf[(size_t)n * 256 + c] = f2bf(acc);
}

// y = LN(x1 + x2) * g + b ; optional f32 and bf16 outputs. block = row (256).
__global__ __launch_bounds__(256) void ln_kernel(
    const float* __restrict__ x1, const float* __restrict__ x2,
    const float* __restrict__ g, const float* __restrict__ b,
    float* __restrict__ outf, bf16* __restrict__ outb) {
  int n = blockIdx.x, tid = threadIdx.x;
  float x = x1[(size_t)n * 256 + tid] + x2[(size_t)n * 256 + tid];
  float s = x, s2 = x * x;
#pragma unroll
  for (int o = 32; o; o >>= 1) {
    s += __shfl_xor(s, o);
    s2 += __shfl_xor(s2, o);
  }
  __shared__ float ls[4], ls2[4];
  int wv = tid >> 6, lane = tid & 63;
  if (lane == 0) {
    ls[wv] = s;
    ls2[wv] = s2;
  }
  __syncthreads();
  s = ls[0] + ls[1] + ls[2] + ls[3];
  s2 = ls2[0] + ls2[1] + ls2[2] + ls2[3];
  float mu = s * (1.f / 256.f);
  float var = s2 * (1.f / 256.f) - mu * mu;
  float y = (x - mu) * rsqrtf(var + 1e-5f) * g[tid] + b[tid];
  if (outf) outf[(size_t)n * 256 + tid] = y;
  if (outb) outb[(size_t)n * 256 + tid] = f2bf(y);
}

// --------------------------- workspace layout ------------------------------
static constexpr size_t OFF_HN = 0;                       // 50000*256 bf16
static constexpr size_t OFF_HE = OFF_HN + 25600000;       // 400000*256 bf16
static constexpr size_t OFF_WQT = OFF_HE + 204800000;     // 256x512 bf16
static constexpr size_t OFF_WKVT = OFF_WQT + 262144;      // 512x512 bf16
static constexpr size_t OFF_WOT = OFF_WKVT + 524288;      // 256x256 bf16
static constexpr size_t OFF_W1T = OFF_WOT + 131072;       // 1024x256 bf16
static constexpr size_t OFF_W2T = OFF_W1T + 524288;       // 256x1024 bf16
static constexpr size_t OFF_SC = OFF_W2T + 524288;        // 400000*4 f32
static constexpr size_t OFF_DEG = OFF_SC + 6400000;       // 50000 i32
static constexpr size_t OFF_OFFS = OFF_DEG + 200000;      // 50001 i32
static constexpr size_t OFF_CUR = OFF_OFFS + 200064;      // 50000 i32
static constexpr size_t OFF_EPERM = OFF_CUR + 200000;     // 400000 i32
static constexpr size_t OFF_AOUT = OFF_EPERM + 1600000;   // 50000*256 bf16
static constexpr size_t OFF_Q = OFF_AOUT + 25600000;      // 400000*256 bf16
static constexpr size_t OFF_V = OFF_Q + 204800000;        // 400000*256 bf16
// aliases: Q dead after KV-GEMM; h_e_bf dead after KV-GEMM.
static constexpr size_t OFF_TMP = OFF_Q;                  // 50000*256 f32
static constexpr size_t OFF_H1F = OFF_Q + 51200000;       // 50000*256 f32
static constexpr size_t OFF_H1B = OFF_Q + 102400000;      // 50000*256 bf16
static constexpr size_t OFF_TMP2 = OFF_Q + 128000000;     // 50000*256 f32
static constexpr size_t OFF_FFM = OFF_HE;                 // 50000*1024 bf16
// total need: OFF_V + 204800000 = 676,166,144 bytes

extern "C" void kernel_launch(void* const* d_in, const int* in_sizes, int n_in,
                              void* d_out, int out_size, void* d_ws,
                              size_t ws_size, hipStream_t stream) {
  const float* h_n = (const float*)d_in[0];
  const float* h_e = (const float*)d_in[1];
  const int* eidx = (const int*)d_in[2];
  const int* src = eidx;
  const int* dst = eidx + NE;
  const float* Wq_w = (const float*)d_in[3];
  const float* Wq_b = (const float*)d_in[4];
  const float* Wkv_w = (const float*)d_in[5];
  const float* Wkv_b = (const float*)d_in[6];
  const float* Wo_w = (const float*)d_in[7];
  const float* Wo_b = (const float*)d_in[8];
  const float* ln1_g = (const float*)d_in[9];
  const float* ln1_b = (const float*)d_in[10];
  const float* f1_w = (const float*)d_in[11];
  const float* f1_b = (const float*)d_in[12];
  const float* f2_w = (const float*)d_in[13];
  const float* f2_b = (const float*)d_in[14];
  const float* ln2_g = (const float*)d_in[15];
  const float* ln2_b = (const float*)d_in[16];

  uint8_t* ws = (uint8_t*)d_ws;
  bf16* hn_bf = (bf16*)(ws + OFF_HN);
  bf16* he_bf = (bf16*)(ws + OFF_HE);
  bf16* WqT = (bf16*)(ws + OFF_WQT);
  bf16* WkvT = (bf16*)(ws + OFF_WKVT);
  bf16* WoT = (bf16*)(ws + OFF_WOT);
  bf16* W1T = (bf16*)(ws + OFF_W1T);
  bf16* W2T = (bf16*)(ws + OFF_W2T);
  float* scores = (float*)(ws + OFF_SC);
  int* deg = (int*)(ws + OFF_DEG);
  int* offs = (int*)(ws + OFF_OFFS);
  int* cursor = (int*)(ws + OFF_CUR);
  int* eperm = (int*)(ws + OFF_EPERM);
  bf16* aout = (bf16*)(ws + OFF_AOUT);
  bf16* Qbf = (bf16*)(ws + OFF_Q);
  bf16* Vbf = (bf16*)(ws + OFF_V);
  float* tmp = (float*)(ws + OFF_TMP);
  float* h1f = (float*)(ws + OFF_H1F);
  bf16* h1b = (bf16*)(ws + OFF_H1B);
  float* tmp2 = (float*)(ws + OFF_TMP2);
  bf16* ffm = (bf16*)(ws + OFF_FFM);

  // 1. casts + weight transposes
  cast_bf16<<<12500, 256, 0, stream>>>(h_n, hn_bf, NN * 256);
  cast_bf16<<<100000, 256, 0, stream>>>(h_e, he_bf, NE * 256);
  transpose_cast<<<512, 256, 0, stream>>>(Wq_w, WqT, 512, 256);
  transpose_cast<<<1024, 256, 0, stream>>>(Wkv_w, WkvT, 512, 512);
  transpose_cast<<<256, 256, 0, stream>>>(Wo_w, WoT, 256, 256);
  transpose_cast<<<1024, 256, 0, stream>>>(f1_w, W1T, 256, 1024);
  transpose_cast<<<1024, 256, 0, stream>>>(f2_w, W2T, 1024, 256);

  // 2. CSR over src
  hipMemsetAsync(deg, 0, NN * sizeof(int), stream);
  count_deg<<<1563, 256, 0, stream>>>(src, deg, NE);
  scan_offs<<<1, 256, 0, stream>>>(deg, offs, cursor, NN);
  scatter_edges<<<1563, 256, 0, stream>>>(src, cursor, eperm, NE);

  // 3. Q-GEMM (gather src), then KV-GEMM (gather dst) with fused scores + V
  gemm_edge<0><<<dim3(3125, 2), 256, 0, stream>>>(hn_bf, he_bf, src, WqT, Wq_b,
                                                  nullptr, Qbf, nullptr);
  gemm_edge<1><<<dim3(3125, 4), 256, 0, stream>>>(hn_bf, he_bf, dst, WkvT,
                                                  Wkv_b, Qbf, Vbf, scores);

  // 4. segment softmax + weighted V
  aggregate<<<NN, 256, 0, stream>>>(offs, eperm, scores, Vbf, aout);

  // 5. Wo projection + LN1
  gemm_node<256, 0><<<dim3(391, 2), 256, 0, stream>>>(aout, NN, WoT, Wo_b, 256,
                                                      tmp, nullptr);
  ln_kernel<<<NN, 256, 0, stream>>>(h_n, tmp, ln1_g, ln1_b, h1f, h1b);

  // 6. FFN + LN2
  gemm_node<256, 1><<<dim3(391, 8), 256, 0, stream>>>(h1b, NN, W1T, f1_b, 1024,
                                                      nullptr, ffm);
  gemm_node<1024, 0><<<dim3(391, 2), 256, 0, stream>>>(ffm, NN, W2T, f2_b, 256,
                                                       tmp2, nullptr);
  ln_kernel<<<NN, 256, 0, stream>>>(h1f, tmp2, ln2_g, ln2_b, (float*)d_out,
                                    nullptr);
}